// Round 22
// baseline (465.648 us; speedup 1.0000x reference)
//
#include <hip/hip_runtime.h>

typedef unsigned short u16;
typedef unsigned int   u32;
typedef short bf16x8 __attribute__((ext_vector_type(8)));
typedef float f32x4  __attribute__((ext_vector_type(4)));
typedef unsigned short u16x4 __attribute__((ext_vector_type(4)));
typedef unsigned int   u32x2 __attribute__((ext_vector_type(2)));

#define HID   512
#define NT    64            // columns per workgroup (1024 threads, 16 waves, 1 block/CU)
#define NCOL  65536
#define KTILES 17           // 16 K-tiles of W + 1 tile carrying {U, bias, 0}
#define BBUF  (KTILES * 4 * 512)         // 34816 u16 per LDS B buffer (68 KB)
#define WMAT_ELEMS (KTILES * 32 * 512)   // 278528 bf16 per matrix

__device__ __forceinline__ float bf2f(u16 v) {
  union { u32 u; float f; } t; t.u = ((u32)v) << 16; return t.f;
}
__device__ __forceinline__ u16 f2bf(float f) {
  union { float f; u32 u; } t; t.f = f;
  u32 r = t.u + 0x7fffu + ((t.u >> 16) & 1u);   // round-to-nearest-even
  return (u16)(r >> 16);
}
__device__ __forceinline__ float lo16(u32 v) { return bf2f((u16)(v & 0xffffu)); }
__device__ __forceinline__ float hi16(u32 v) { return bf2f((u16)(v >> 16)); }
// packed bf16 convert: 1 VOP3 replaces ~9 VALU of manual RNE bit-twiddle
__device__ __forceinline__ u32 pk2(float lo, float hi) {
  u32 r;
  asm("v_cvt_pk_bf16_f32 %0, %1, %2" : "=v"(r) : "v"(lo), "v"(hi));
  return r;
}
// flag-aware scalar load: isbf ? bf16[i] : f32[i]
__device__ __forceinline__ float ldv(const void* p, int i, int isbf) {
  return isbf ? bf2f(((const u16*)p)[i]) : ((const float*)p)[i];
}
// tanh(x) = 1 - 2/(exp(2x)+1), exp via v_exp_f32 (exp2)
__device__ __forceinline__ float tanh_fast(float x) {
  float e = __builtin_amdgcn_exp2f(x * 2.8853900817779268f); // 2*log2(e)
  return 1.0f - 2.0f * __builtin_amdgcn_rcpf(e + 1.0f);
}

// Fragment-linear LDS B layout: element (col c in 0..63, k in 0..543) lives at
// boff(c,k). Tile (kb=k>>5, ct=c>>4) holds 1024 u16 in MFMA lane order: lane
// L = ((k>>3)&3)*16 + (c&15) owns 8 consecutive k. gemm ds_read_b128 is
// lane*16B linear -> zero bank conflicts (R13 verified).
__device__ __forceinline__ int boff(int c, int k) {
  return ((k >> 5) * 4 + (c >> 4)) * 512 + ((k >> 3) & 3) * 128 + (c & 15) * 8 + (k & 7);
}

// ---------------- dtype sniff ----------------
__global__ void sniff_kernel(const u16* x, u32* flag) {
  if (threadIdx.x == 0 && blockIdx.x == 0) {
    int cnt = 0;
    for (int i = 0; i < 256; i++) {
      u32 e = (x[i] >> 7) & 0xFFu;
      if (e == 0u || (e >= 100u && e <= 140u)) cnt++;
    }
    *flag = (cnt >= 220) ? 1u : 0u;
  }
}

// ---------------- U/bias pre-pack (S1 weights + Wout only now) ----------------
struct PrepArgs {
  const void* U[9]; const void* B[9];
  const void* Wout; const void* bout;
  float* dst; const u32* flag;
};

__global__ void prep_kernel(PrepArgs a) {
  int t = blockIdx.x * 256 + threadIdx.x;     // 5120 threads
  const int isbf = (int)*a.flag;
  if (t < 9 * 512) {
    int m = t >> 9, r = t & 511;
    float4 v;
    v.x = ldv(a.U[m], r * 3 + 0, isbf);
    v.y = ldv(a.U[m], r * 3 + 1, isbf);
    v.z = ldv(a.U[m], r * 3 + 2, isbf);
    v.w = ldv(a.B[m], r, isbf);
    ((float4*)a.dst)[t] = v;
  } else if (t < 9 * 512 + 512) {
    int r = t - 9 * 512;
    a.dst[9 * 2048 + r] = ldv(a.Wout, r, isbf);
    if (r == 0) a.dst[9 * 2048 + 512] = ldv(a.bout, 0, isbf);
  }
}

// ---------------- weight swizzle pre-pass ----------------
struct SwzArgs {
  const void* src[8];   // Wz1,Wg1,Wr1,Wh1,Wz2,Wg2,Wr2,Wh2
  const void* usrc[8];  // Uz1,Ug1,Ur1,Uh1,Uz2,Ug2,Ur2,Uh2
  const void* bsrc[8];  // bz1,bg1,br1,bh1,bz2,bg2,br2,bh2
  u16* dst; const u32* flag;
};

__global__ void swizzle_kernel(SwzArgs a) {
  const int isbf = (int)*a.flag;
  int t = blockIdx.x * 256 + threadIdx.x;        // 278528 threads total
  int m    = t / (KTILES * 32 * 64);             // matrix 0..7
  int rem  = t - m * (KTILES * 32 * 64);
  int tile = rem >> 6;                           // 0..543
  int lane = rem & 63;
  int kb = tile >> 5, rt = tile & 31;
  int row = rt * 16 + (lane & 15);
  int kk  = (lane >> 4) * 8;
  u16 tmp[8];
  if (kb < 16) {
    int k = kb * 32 + kk;
    if (isbf) {
      const u16* s = (const u16*)a.src[m] + row * 512 + k;
#pragma unroll
      for (int j = 0; j < 8; j++) tmp[j] = s[j];
    } else {
      const float* s = (const float*)a.src[m] + row * 512 + k;
#pragma unroll
      for (int j = 0; j < 8; j++) tmp[j] = f2bf(s[j]);
    }
  } else {
#pragma unroll
    for (int j = 0; j < 8; j++) {
      int kidx = kk + j;
      float v = (kidx < 3) ? ldv(a.usrc[m], row * 3 + kidx, isbf)
              : (kidx == 3) ? ldv(a.bsrc[m], row, isbf)
              : 0.0f;
      tmp[j] = f2bf(v);
    }
  }
  uint4* d = (uint4*)(a.dst + (size_t)m * WMAT_ELEMS + (size_t)tile * 512 + lane * 8);
  *d = *(const uint4*)tmp;
}

// ---------------- fused network kernel ----------------
// 1024 threads = 16 waves; wave = 32-row slab, acc[2][4] = ALL 64 cols.
// R21 books (revised: VALUBusy superset of MFMA issue): 41% MFMA + ~5% true
// VALU + ~54% latency STALL at 2 waves/SIMD. This config combines R19's
// halved A-port traffic (16 x 34KB = 557KB/CU/gemm, unchanged) with 4
// waves/SIMD for latency hiding — the combination never tested (R5-R13
// 4-wave configs all carried 1088KB). Register budget 128/wave: acc 32 +
// zpk/opk 32 + a 16 + b 16 + addr ~20 = ~116 (R5-proven shape). SGB weave
// reverted (R21: -1.5%).
struct KArgs {
  const void* x;
  const u16* ws;        // swizzled [W | U bias 0] per gate matrix (bf16)
  const float4* ub;     // mat8 = {W1,b1} rows for S1; then 512 f32 Wout + bout
  const u32* flag;
  void* out;
};

// 32(M-slab) x 544(Kext) x 64(N) GEMM step: A from swizzled global via 2-slot
// rotating prefetch, B from fragment-linear LDS. acc zero-init by caller.
__device__ __forceinline__ void gemm64(f32x4 acc[2][4],
    const u16* __restrict__ wmat, const u16* ldsB, int wave, int lane)
{
  const u16* abase = wmat + (size_t)(wave * 2) * 512 + lane * 8;
  const u16* bbase = ldsB + lane * 8;
  bf16x8 a[2][2];
#pragma unroll
  for (int i = 0; i < 2; i++)
    a[0][i] = *(const bf16x8*)(abase + i * 512);
#pragma unroll
  for (int kb = 0; kb < KTILES; kb++) {
    if (kb + 1 < KTILES) {
#pragma unroll
      for (int i = 0; i < 2; i++)
        a[(kb + 1) & 1][i] = *(const bf16x8*)(abase + (size_t)(kb + 1) * 16384 + i * 512);
    }
    bf16x8 b[4];
#pragma unroll
    for (int ct = 0; ct < 4; ct++)
      b[ct] = *(const bf16x8*)(bbase + (kb * 4 + ct) * 512);
    __builtin_amdgcn_s_setprio(1);
#pragma unroll
    for (int rt = 0; rt < 2; rt++)
#pragma unroll
      for (int ct = 0; ct < 4; ct++)
        acc[rt][ct] = __builtin_amdgcn_mfma_f32_16x16x32_bf16(a[kb & 1][rt], b[ct], acc[rt][ct], 0, 0, 0);
    __builtin_amdgcn_s_setprio(0);
  }
}

__global__ __launch_bounds__(1024, 4) void pdenet_kernel(KArgs ka) {
  __shared__ __align__(16) u16 ldsS[BBUF];   // hidden state S (fragment-linear)
  __shared__ __align__(16) u16 ldsR[BBUF];   // S*R buffer (fragment-linear)
  __shared__ float xs[3 * NT];

  const int isbf = (int)*ka.flag;
  const int tid  = threadIdx.x;
  const int wave = tid >> 6;          // 0..15 -> 32-row slab
  const int lane = tid & 63;
  const int l15  = lane & 15;
  const int quad = lane >> 4;
  const int c0   = blockIdx.x * NT;

  if (tid < 3 * NT)
    xs[tid] = ldv(ka.x, (tid >> 6) * NCOL + c0 + (tid & 63), isbf);
  __syncthreads();

  // S1 = tanh(W1@x + b1): thread = (row, col-half), 32 columns each, with
  // per-lane rotation to spread scalar-write banks.
  {
    int r  = tid & 511;
    int ch = tid >> 9;                // 0..1
    float4 w = ka.ub[8 * 512 + r];
#pragma unroll 4
    for (int cc = 0; cc < 32; cc++) {
      int c = ch * 32 + ((cc + lane) & 31);
      float s = tanh_fast(w.x * xs[c] + w.y * xs[NT + c] + w.z * xs[2 * NT + c] + w.w);
      ldsS[boff(c, r)] = f2bf(s);
    }
  }

  // K-extension k=512..543 of both buffers: {x0,x1,x2,1,0,...} per column.
  {
#pragma unroll
    for (int rep = 0; rep < 2; rep++) {
      int e = tid + rep * 1024;       // 2048 entries per buffer
      int c = e >> 5, j = e & 31;
      float v = (j == 0) ? xs[c] : (j == 1) ? xs[NT + c]
              : (j == 2) ? xs[2 * NT + c] : (j == 3) ? 1.0f : 0.0f;
      u16 bv = f2bf(v);
      int o = boff(c, 512 + j);
      ldsS[o] = bv;
      ldsR[o] = bv;
    }
  }
  __syncthreads();

  // zpk: holds tanh(Z) packed, then (after R-epi) Z*S packed.
  // opk: holds (1-tanh(G)) packed.
  u32 zpk[2][4][2], opk[2][4][2];

#pragma unroll
  for (int layer = 0; layer < 2; layer++) {
    const int g0 = layer * 4;

    // ---- Z = tanh([Wz|Uz b]@[S;x;1]) -> zpk ----
    {
      f32x4 acc[2][4] = {};
      gemm64(acc, ka.ws + (size_t)(g0 + 0) * WMAT_ELEMS, ldsS, wave, lane);
#pragma unroll
      for (int rt = 0; rt < 2; rt++)
#pragma unroll
        for (int ct = 0; ct < 4; ct++) {
          zpk[rt][ct][0] = pk2(tanh_fast(acc[rt][ct][0]), tanh_fast(acc[rt][ct][1]));
          zpk[rt][ct][1] = pk2(tanh_fast(acc[rt][ct][2]), tanh_fast(acc[rt][ct][3]));
        }
    }
    // ---- G -> opk = 1 - tanh(G) ----
    {
      f32x4 acc[2][4] = {};
      gemm64(acc, ka.ws + (size_t)(g0 + 1) * WMAT_ELEMS, ldsS, wave, lane);
#pragma unroll
      for (int rt = 0; rt < 2; rt++)
#pragma unroll
        for (int ct = 0; ct < 4; ct++) {
          opk[rt][ct][0] = pk2(1.0f - tanh_fast(acc[rt][ct][0]),
                               1.0f - tanh_fast(acc[rt][ct][1]));
          opk[rt][ct][1] = pk2(1.0f - tanh_fast(acc[rt][ct][2]),
                               1.0f - tanh_fast(acc[rt][ct][3]));
        }
    }
    // ---- R; write SR = S*R -> ldsR; fold Z*S into zpk (registers) ----
    {
      f32x4 acc[2][4] = {};
      gemm64(acc, ka.ws + (size_t)(g0 + 2) * WMAT_ELEMS, ldsS, wave, lane);
#pragma unroll
      for (int rt = 0; rt < 2; rt++)
#pragma unroll
        for (int ct = 0; ct < 4; ct++) {
          int c  = ct * 16 + l15;
          int rb = wave * 32 + rt * 16 + quad * 4;
          int o  = boff(c, rb);
          u16x4 sv4 = *(const u16x4*)&ldsS[o];
          float sv0 = bf2f(sv4[0]), sv1 = bf2f(sv4[1]);
          float sv2 = bf2f(sv4[2]), sv3 = bf2f(sv4[3]);
          u32x2 sr;
          sr[0] = pk2(sv0 * tanh_fast(acc[rt][ct][0]), sv1 * tanh_fast(acc[rt][ct][1]));
          sr[1] = pk2(sv2 * tanh_fast(acc[rt][ct][2]), sv3 * tanh_fast(acc[rt][ct][3]));
          u32 zp0 = zpk[rt][ct][0], zp1 = zpk[rt][ct][1];
          zpk[rt][ct][0] = pk2(lo16(zp0) * sv0, hi16(zp0) * sv1);
          zpk[rt][ct][1] = pk2(lo16(zp1) * sv2, hi16(zp1) * sv3);
          *(u32x2*)&ldsR[o] = sr;
        }
    }
    __syncthreads();   // publish SR for all waves
    // ---- H = tanh([Wh|Uh b]@[SR;x;1]); S_next = (1-G)*H + Z*S -> ldsS ----
    // (1-G) and Z*S live in registers: zero LDS reads in this epilogue.
    {
      f32x4 acc[2][4] = {};
      gemm64(acc, ka.ws + (size_t)(g0 + 3) * WMAT_ELEMS, ldsR, wave, lane);
#pragma unroll
      for (int rt = 0; rt < 2; rt++)
#pragma unroll
        for (int ct = 0; ct < 4; ct++) {
          int c  = ct * 16 + l15;
          int rb = wave * 32 + rt * 16 + quad * 4;
          u32 zp0 = zpk[rt][ct][0], zp1 = zpk[rt][ct][1];
          u32 op0 = opk[rt][ct][0], op1 = opk[rt][ct][1];
          u32x2 sn;
          sn[0] = pk2(lo16(op0) * tanh_fast(acc[rt][ct][0]) + lo16(zp0),
                      hi16(op0) * tanh_fast(acc[rt][ct][1]) + hi16(zp0));
          sn[1] = pk2(lo16(op1) * tanh_fast(acc[rt][ct][2]) + lo16(zp1),
                      hi16(op1) * tanh_fast(acc[rt][ct][3]) + hi16(zp1));
          *(u32x2*)&ldsS[boff(c, rb)] = sn;
        }
    }
    __syncthreads();   // publish S_next
  }

  // ---- out = W @ S3 + b : 16 threads per column, shuffle-reduce ----
  {
    int c   = tid >> 4;               // 0..63
    int seg = tid & 15;
    const float* wv = (const float*)(ka.ub + 9 * 512);   // 512 f32 Wout + bout
    const float4* w4 = (const float4*)(wv + seg * 32);
    float p = 0.0f;
#pragma unroll
    for (int j = 0; j < 8; j++) {
      u16x4 sv = *(const u16x4*)&ldsS[boff(c, seg * 32 + j * 4)];
      float4 w = w4[j];
      p += w.x * bf2f(sv[0]) + w.y * bf2f(sv[1]) + w.z * bf2f(sv[2]) + w.w * bf2f(sv[3]);
    }
    p += __shfl_xor(p, 1);
    p += __shfl_xor(p, 2);
    p += __shfl_xor(p, 4);
    p += __shfl_xor(p, 8);
    if (seg == 0) {
      float res = p + wv[512];
      if (isbf) ((u16*)ka.out)[c0 + c] = f2bf(res);
      else      ((float*)ka.out)[c0 + c] = res;
    }
  }
}

extern "C" void kernel_launch(void* const* d_in, const int* in_sizes, int n_in,
                              void* d_out, int out_size, void* d_ws, size_t ws_size,
                              hipStream_t stream) {
  // setup_inputs order:
  // 0:x 1:W1 2:b1 | 3:Uz1 4:Wz1 5:bz1 | 6:Ug1 7:Wg1 8:bg1 | 9:Ur1 10:Wr1 11:br1
  // 12:Uh1 13:Wh1 14:bh1 | 15:Uz2 16:Wz2 17:bz2 | 18:Ug2 19:Wg2 20:bg2
  // 21:Ur2 22:Wr2 23:br2 | 24:Uh2 25:Wh2 26:bh2 | 27:W 28:b
  static const int widx[8] = {4, 7, 10, 13, 16, 19, 22, 25};
  static const int uidx[8] = {3, 6, 9, 12, 15, 18, 21, 24};
  static const int bidx[8] = {5, 8, 11, 14, 17, 20, 23, 26};

  u16*   ws16  = (u16*)d_ws;
  u32*   flagp = (u32*)((char*)d_ws + (size_t)8 * WMAT_ELEMS * 2);        // ~4.25 MiB
  float* ubp   = (float*)((char*)d_ws + (size_t)8 * WMAT_ELEMS * 2 + 16); // +16 B

  hipLaunchKernelGGL(sniff_kernel, dim3(1), dim3(64), 0, stream,
                     (const u16*)d_in[0], flagp);

  PrepArgs pa;
  for (int i = 0; i < 8; i++) { pa.U[i] = d_in[uidx[i]]; pa.B[i] = d_in[bidx[i]]; }
  pa.U[8] = d_in[1]; pa.B[8] = d_in[2];
  pa.Wout = d_in[27]; pa.bout = d_in[28];
  pa.dst = ubp; pa.flag = flagp;
  hipLaunchKernelGGL(prep_kernel, dim3(20), dim3(256), 0, stream, pa);

  SwzArgs sa;
  for (int i = 0; i < 8; i++) {
    sa.src[i]  = d_in[widx[i]];
    sa.usrc[i] = d_in[uidx[i]];
    sa.bsrc[i] = d_in[bidx[i]];
  }
  sa.dst  = ws16;
  sa.flag = flagp;
  hipLaunchKernelGGL(swizzle_kernel, dim3(1088), dim3(256), 0, stream, sa);

  KArgs ka;
  ka.x    = d_in[0];
  ka.ws   = ws16;
  ka.ub   = (const float4*)ubp;
  ka.flag = flagp;
  ka.out  = d_out;
  hipLaunchKernelGGL(pdenet_kernel, dim3(NCOL / NT), dim3(1024), 0, stream, ka);
}

// Round 23
// 420.488 us; speedup vs baseline: 1.1074x; 1.1074x over previous
//
#include <hip/hip_runtime.h>

typedef unsigned short u16;
typedef unsigned int   u32;
typedef short bf16x8 __attribute__((ext_vector_type(8)));
typedef float f32x4  __attribute__((ext_vector_type(4)));
typedef unsigned short u16x4 __attribute__((ext_vector_type(4)));
typedef unsigned int   u32x2 __attribute__((ext_vector_type(2)));

#define HID   512
#define NT    64            // columns per workgroup (512 threads, 8 waves, 1 block/CU)
#define NCOL  65536
#define KTILES 17           // 16 K-tiles of W + 1 tile carrying {U, bias, 0}
#define BBUF  (KTILES * 4 * 512)         // 34816 u16 per LDS B buffer (68 KB)
#define WMAT_ELEMS (KTILES * 32 * 512)   // 278528 bf16 per matrix

__device__ __forceinline__ float bf2f(u16 v) {
  union { u32 u; float f; } t; t.u = ((u32)v) << 16; return t.f;
}
__device__ __forceinline__ u16 f2bf(float f) {
  union { float f; u32 u; } t; t.f = f;
  u32 r = t.u + 0x7fffu + ((t.u >> 16) & 1u);   // round-to-nearest-even
  return (u16)(r >> 16);
}
__device__ __forceinline__ float lo16(u32 v) { return bf2f((u16)(v & 0xffffu)); }
__device__ __forceinline__ float hi16(u32 v) { return bf2f((u16)(v >> 16)); }
// packed bf16 convert: 1 VOP3 replaces ~9 VALU of manual RNE bit-twiddle
__device__ __forceinline__ u32 pk2(float lo, float hi) {
  u32 r;
  asm("v_cvt_pk_bf16_f32 %0, %1, %2" : "=v"(r) : "v"(lo), "v"(hi));
  return r;
}
// flag-aware scalar load: isbf ? bf16[i] : f32[i]
__device__ __forceinline__ float ldv(const void* p, int i, int isbf) {
  return isbf ? bf2f(((const u16*)p)[i]) : ((const float*)p)[i];
}
// tanh(x) = 1 - 2/(exp(2x)+1), exp via v_exp_f32 (exp2)
__device__ __forceinline__ float tanh_fast(float x) {
  float e = __builtin_amdgcn_exp2f(x * 2.8853900817779268f); // 2*log2(e)
  return 1.0f - 2.0f * __builtin_amdgcn_rcpf(e + 1.0f);
}

// Fragment-linear LDS B layout: element (col c in 0..63, k in 0..543) lives at
// boff(c,k). gemm ds_read_b128 is lane*16B linear -> zero bank conflicts.
__device__ __forceinline__ int boff(int c, int k) {
  return ((k >> 5) * 4 + (c >> 4)) * 512 + ((k >> 3) & 3) * 128 + (c & 15) * 8 + (k & 7);
}

// ---------------- dtype sniff ----------------
__global__ void sniff_kernel(const u16* x, u32* flag) {
  if (threadIdx.x == 0 && blockIdx.x == 0) {
    int cnt = 0;
    for (int i = 0; i < 256; i++) {
      u32 e = (x[i] >> 7) & 0xFFu;
      if (e == 0u || (e >= 100u && e <= 140u)) cnt++;
    }
    *flag = (cnt >= 220) ? 1u : 0u;
  }
}

// ---------------- U/bias pre-pack (S1 weights + Wout only now) ----------------
struct PrepArgs {
  const void* U[9]; const void* B[9];
  const void* Wout; const void* bout;
  float* dst; const u32* flag;
};

__global__ void prep_kernel(PrepArgs a) {
  int t = blockIdx.x * 256 + threadIdx.x;     // 5120 threads
  const int isbf = (int)*a.flag;
  if (t < 9 * 512) {
    int m = t >> 9, r = t & 511;
    float4 v;
    v.x = ldv(a.U[m], r * 3 + 0, isbf);
    v.y = ldv(a.U[m], r * 3 + 1, isbf);
    v.z = ldv(a.U[m], r * 3 + 2, isbf);
    v.w = ldv(a.B[m], r, isbf);
    ((float4*)a.dst)[t] = v;
  } else if (t < 9 * 512 + 512) {
    int r = t - 9 * 512;
    a.dst[9 * 2048 + r] = ldv(a.Wout, r, isbf);
    if (r == 0) a.dst[9 * 2048 + 512] = ldv(a.bout, 0, isbf);
  }
}

// ---------------- weight swizzle pre-pass ----------------
struct SwzArgs {
  const void* src[8];   // Wz1,Wg1,Wr1,Wh1,Wz2,Wg2,Wr2,Wh2
  const void* usrc[8];  // Uz1,Ug1,Ur1,Uh1,Uz2,Ug2,Ur2,Uh2
  const void* bsrc[8];  // bz1,bg1,br1,bh1,bz2,bg2,br2,bh2
  u16* dst; const u32* flag;
};

__global__ void swizzle_kernel(SwzArgs a) {
  const int isbf = (int)*a.flag;
  int t = blockIdx.x * 256 + threadIdx.x;        // 278528 threads total
  int m    = t / (KTILES * 32 * 64);             // matrix 0..7
  int rem  = t - m * (KTILES * 32 * 64);
  int tile = rem >> 6;                           // 0..543
  int lane = rem & 63;
  int kb = tile >> 5, rt = tile & 31;
  int row = rt * 16 + (lane & 15);
  int kk  = (lane >> 4) * 8;
  u16 tmp[8];
  if (kb < 16) {
    int k = kb * 32 + kk;
    if (isbf) {
      const u16* s = (const u16*)a.src[m] + row * 512 + k;
#pragma unroll
      for (int j = 0; j < 8; j++) tmp[j] = s[j];
    } else {
      const float* s = (const float*)a.src[m] + row * 512 + k;
#pragma unroll
      for (int j = 0; j < 8; j++) tmp[j] = f2bf(s[j]);
    }
  } else {
#pragma unroll
    for (int j = 0; j < 8; j++) {
      int kidx = kk + j;
      float v = (kidx < 3) ? ldv(a.usrc[m], row * 3 + kidx, isbf)
              : (kidx == 3) ? ldv(a.bsrc[m], row, isbf)
              : 0.0f;
      tmp[j] = f2bf(v);
    }
  }
  uint4* d = (uint4*)(a.dst + (size_t)m * WMAT_ELEMS + (size_t)tile * 512 + lane * 8);
  *d = *(const uint4*)tmp;
}

// ---------------- fused network kernel ----------------
// 512 threads = 8 waves; wave = rowslab (64-row slab), acc[4][4] = ALL 64 cols
// (R19 port-traffic win kept). R22 lesson: 4-wave ALWAYS spills this working
// set -> stay at 2 waves/SIMD and kill the R19 spill instead. Dependency-
// ordered units Z -> R -> G -> H: after G-gemm, ldsS is DEAD (readers Z/R/G
// done; H reads ldsR), so G-epi writes (1-tanh G) directly into ldsS and
// H-epi reads it back (own-thread elements) before overwriting with S_next.
// opk never crosses a gemm in registers: -32 live regs at every gemm after Z.
// Peak live ~64 AGPR + ~92 VGPR -> no spill expected (falsifier: WRITE_SIZE).
struct KArgs {
  const void* x;
  const u16* ws;        // swizzled [W | U bias 0] per gate matrix (bf16)
  const float4* ub;     // mat8 = {W1,b1} rows for S1; then 512 f32 Wout + bout
  const u32* flag;
  void* out;
};

// 64(M-slab) x 544(Kext) x 64(N) GEMM step: A from swizzled global via 2-slot
// rotating prefetch, B from fragment-linear LDS. acc zero-init by caller.
__device__ __forceinline__ void gemm64(f32x4 acc[4][4],
    const u16* __restrict__ wmat, const u16* ldsB, int rowslab, int lane)
{
  const u16* abase = wmat + (size_t)(rowslab * 4) * 512 + lane * 8;
  const u16* bbase = ldsB + lane * 8;
  bf16x8 a[2][4];
#pragma unroll
  for (int i = 0; i < 4; i++)
    a[0][i] = *(const bf16x8*)(abase + i * 512);
#pragma unroll
  for (int kb = 0; kb < KTILES; kb++) {
    if (kb + 1 < KTILES) {
#pragma unroll
      for (int i = 0; i < 4; i++)
        a[(kb + 1) & 1][i] = *(const bf16x8*)(abase + (size_t)(kb + 1) * 16384 + i * 512);
    }
    bf16x8 b[4];
#pragma unroll
    for (int ct = 0; ct < 4; ct++)
      b[ct] = *(const bf16x8*)(bbase + (kb * 4 + ct) * 512);
    __builtin_amdgcn_s_setprio(1);
#pragma unroll
    for (int rt = 0; rt < 4; rt++)
#pragma unroll
      for (int ct = 0; ct < 4; ct++)
        acc[rt][ct] = __builtin_amdgcn_mfma_f32_16x16x32_bf16(a[kb & 1][rt], b[ct], acc[rt][ct], 0, 0, 0);
    __builtin_amdgcn_s_setprio(0);
  }
}

__global__ __launch_bounds__(512, 2) void pdenet_kernel(KArgs ka) {
  __shared__ __align__(16) u16 ldsS[BBUF];   // S, then (1-G) scratch, then S_next
  __shared__ __align__(16) u16 ldsR[BBUF];   // S*R buffer (fragment-linear)
  __shared__ float xs[3 * NT];

  const int isbf = (int)*ka.flag;
  const int tid  = threadIdx.x;
  const int rowslab = tid >> 6;       // wave 0..7 -> 64-row slab
  const int lane = tid & 63;
  const int l15  = lane & 15;
  const int quad = lane >> 4;
  const int c0   = blockIdx.x * NT;

  if (tid < 3 * NT)
    xs[tid] = ldv(ka.x, (tid >> 6) * NCOL + c0 + (tid & 63), isbf);
  __syncthreads();

  // S1 = tanh(W1@x + b1): thread = row, iterate 64 columns (rotated).
  {
    int r = tid;
    float4 w = ka.ub[8 * 512 + r];
#pragma unroll 4
    for (int cc = 0; cc < NT; cc++) {
      int c = (cc + lane) & 63;
      float s = tanh_fast(w.x * xs[c] + w.y * xs[NT + c] + w.z * xs[2 * NT + c] + w.w);
      ldsS[boff(c, r)] = f2bf(s);
    }
  }

  // K-extension k=512..543 of both buffers: {x0,x1,x2,1,0,...} per column.
  {
#pragma unroll
    for (int rep = 0; rep < 4; rep++) {
      int e = tid + rep * 512;        // 2048 entries per buffer
      int c = e >> 5, j = e & 31;
      float v = (j == 0) ? xs[c] : (j == 1) ? xs[NT + c]
              : (j == 2) ? xs[2 * NT + c] : (j == 3) ? 1.0f : 0.0f;
      u16 bv = f2bf(v);
      int o = boff(c, 512 + j);
      ldsS[o] = bv;
      ldsR[o] = bv;
    }
  }
  __syncthreads();

  // zpk: holds tanh(Z) packed, then (after R-epi) Z*S packed.
  u32 zpk[4][4][2];

#pragma unroll
  for (int layer = 0; layer < 2; layer++) {
    const int g0 = layer * 4;

    // ---- Z = tanh([Wz|Uz b]@[S;x;1]) -> zpk ----
    {
      f32x4 acc[4][4] = {};
      gemm64(acc, ka.ws + (size_t)(g0 + 0) * WMAT_ELEMS, ldsS, rowslab, lane);
#pragma unroll
      for (int rt = 0; rt < 4; rt++)
#pragma unroll
        for (int ct = 0; ct < 4; ct++) {
          zpk[rt][ct][0] = pk2(tanh_fast(acc[rt][ct][0]), tanh_fast(acc[rt][ct][1]));
          zpk[rt][ct][1] = pk2(tanh_fast(acc[rt][ct][2]), tanh_fast(acc[rt][ct][3]));
        }
    }
    // ---- R; write SR = S*R -> ldsR; fold Z*S into zpk (registers) ----
    {
      f32x4 acc[4][4] = {};
      gemm64(acc, ka.ws + (size_t)(g0 + 2) * WMAT_ELEMS, ldsS, rowslab, lane);
#pragma unroll
      for (int rt = 0; rt < 4; rt++)
#pragma unroll
        for (int ct = 0; ct < 4; ct++) {
          int c  = ct * 16 + l15;
          int rb = rowslab * 64 + rt * 16 + quad * 4;
          int o  = boff(c, rb);
          u16x4 sv4 = *(const u16x4*)&ldsS[o];
          float sv0 = bf2f(sv4[0]), sv1 = bf2f(sv4[1]);
          float sv2 = bf2f(sv4[2]), sv3 = bf2f(sv4[3]);
          u32x2 sr;
          sr[0] = pk2(sv0 * tanh_fast(acc[rt][ct][0]), sv1 * tanh_fast(acc[rt][ct][1]));
          sr[1] = pk2(sv2 * tanh_fast(acc[rt][ct][2]), sv3 * tanh_fast(acc[rt][ct][3]));
          u32 zp0 = zpk[rt][ct][0], zp1 = zpk[rt][ct][1];
          zpk[rt][ct][0] = pk2(lo16(zp0) * sv0, hi16(zp0) * sv1);
          zpk[rt][ct][1] = pk2(lo16(zp1) * sv2, hi16(zp1) * sv3);
          *(u32x2*)&ldsR[o] = sr;
        }
    }
    // ---- G gemm (LAST reader of ldsS) ----
    {
      f32x4 acc[4][4] = {};
      gemm64(acc, ka.ws + (size_t)(g0 + 1) * WMAT_ELEMS, ldsS, rowslab, lane);
      __syncthreads();   // all ldsS reads (Z,R,G) done; all ldsR writes (R-epi) visible
      // ---- G-epi: write (1 - tanh G) DIRECTLY into dead ldsS (own block) ----
#pragma unroll
      for (int rt = 0; rt < 4; rt++)
#pragma unroll
        for (int ct = 0; ct < 4; ct++) {
          int c  = ct * 16 + l15;
          int rb = rowslab * 64 + rt * 16 + quad * 4;
          u32x2 og;
          og[0] = pk2(1.0f - tanh_fast(acc[rt][ct][0]), 1.0f - tanh_fast(acc[rt][ct][1]));
          og[1] = pk2(1.0f - tanh_fast(acc[rt][ct][2]), 1.0f - tanh_fast(acc[rt][ct][3]));
          *(u32x2*)&ldsS[boff(c, rb)] = og;
        }
    }
    // ---- H = tanh([Wh|Uh b]@[SR;x;1]); S_next = (1-G)*H + Z*S -> ldsS ----
    // (1-G) read back from ldsS (own-thread elements, written above by the
    // same thread); Z*S in registers. S_next overwrites the (1-G) slot.
    {
      f32x4 acc[4][4] = {};
      gemm64(acc, ka.ws + (size_t)(g0 + 3) * WMAT_ELEMS, ldsR, rowslab, lane);
#pragma unroll
      for (int rt = 0; rt < 4; rt++)
#pragma unroll
        for (int ct = 0; ct < 4; ct++) {
          int c  = ct * 16 + l15;
          int rb = rowslab * 64 + rt * 16 + quad * 4;
          int o  = boff(c, rb);
          u16x4 og4 = *(const u16x4*)&ldsS[o];
          u32 zp0 = zpk[rt][ct][0], zp1 = zpk[rt][ct][1];
          u32x2 sn;
          sn[0] = pk2(bf2f(og4[0]) * tanh_fast(acc[rt][ct][0]) + lo16(zp0),
                      bf2f(og4[1]) * tanh_fast(acc[rt][ct][1]) + hi16(zp0));
          sn[1] = pk2(bf2f(og4[2]) * tanh_fast(acc[rt][ct][2]) + lo16(zp1),
                      bf2f(og4[3]) * tanh_fast(acc[rt][ct][3]) + hi16(zp1));
          *(u32x2*)&ldsS[o] = sn;
        }
    }
    __syncthreads();   // publish S_next
  }

  // ---- out = W @ S3 + b : 8 threads per column, shuffle-reduce ----
  {
    int c   = tid >> 3;               // 0..63
    int seg = tid & 7;
    const float* wv = (const float*)(ka.ub + 9 * 512);   // 512 f32 Wout + bout
    const float4* w4 = (const float4*)(wv + seg * 64);
    float p = 0.0f;
#pragma unroll
    for (int j = 0; j < 16; j++) {
      u16x4 sv = *(const u16x4*)&ldsS[boff(c, seg * 64 + j * 4)];
      float4 w = w4[j];
      p += w.x * bf2f(sv[0]) + w.y * bf2f(sv[1]) + w.z * bf2f(sv[2]) + w.w * bf2f(sv[3]);
    }
    p += __shfl_xor(p, 1);
    p += __shfl_xor(p, 2);
    p += __shfl_xor(p, 4);
    if (seg == 0) {
      float res = p + wv[512];
      if (isbf) ((u16*)ka.out)[c0 + c] = f2bf(res);
      else      ((float*)ka.out)[c0 + c] = res;
    }
  }
}

extern "C" void kernel_launch(void* const* d_in, const int* in_sizes, int n_in,
                              void* d_out, int out_size, void* d_ws, size_t ws_size,
                              hipStream_t stream) {
  // setup_inputs order:
  // 0:x 1:W1 2:b1 | 3:Uz1 4:Wz1 5:bz1 | 6:Ug1 7:Wg1 8:bg1 | 9:Ur1 10:Wr1 11:br1
  // 12:Uh1 13:Wh1 14:bh1 | 15:Uz2 16:Wz2 17:bz2 | 18:Ug2 19:Wg2 20:bg2
  // 21:Ur2 22:Wr2 23:br2 | 24:Uh2 25:Wh2 26:bh2 | 27:W 28:b
  static const int widx[8] = {4, 7, 10, 13, 16, 19, 22, 25};
  static const int uidx[8] = {3, 6, 9, 12, 15, 18, 21, 24};
  static const int bidx[8] = {5, 8, 11, 14, 17, 20, 23, 26};

  u16*   ws16  = (u16*)d_ws;
  u32*   flagp = (u32*)((char*)d_ws + (size_t)8 * WMAT_ELEMS * 2);        // ~4.25 MiB
  float* ubp   = (float*)((char*)d_ws + (size_t)8 * WMAT_ELEMS * 2 + 16); // +16 B

  hipLaunchKernelGGL(sniff_kernel, dim3(1), dim3(64), 0, stream,
                     (const u16*)d_in[0], flagp);

  PrepArgs pa;
  for (int i = 0; i < 8; i++) { pa.U[i] = d_in[uidx[i]]; pa.B[i] = d_in[bidx[i]]; }
  pa.U[8] = d_in[1]; pa.B[8] = d_in[2];
  pa.Wout = d_in[27]; pa.bout = d_in[28];
  pa.dst = ubp; pa.flag = flagp;
  hipLaunchKernelGGL(prep_kernel, dim3(20), dim3(256), 0, stream, pa);

  SwzArgs sa;
  for (int i = 0; i < 8; i++) {
    sa.src[i]  = d_in[widx[i]];
    sa.usrc[i] = d_in[uidx[i]];
    sa.bsrc[i] = d_in[bidx[i]];
  }
  sa.dst  = ws16;
  sa.flag = flagp;
  hipLaunchKernelGGL(swizzle_kernel, dim3(1088), dim3(256), 0, stream, sa);

  KArgs ka;
  ka.x    = d_in[0];
  ka.ws   = ws16;
  ka.ub   = (const float4*)ubp;
  ka.flag = flagp;
  ka.out  = d_out;
  hipLaunchKernelGGL(pdenet_kernel, dim3(NCOL / NT), dim3(512), 0, stream, ka);
}